// Round 16
// baseline (119.909 us; speedup 1.0000x reference)
//
#include <hip/hip_runtime.h>
#include <hip/hip_bf16.h>

// NARX forward via bf16 MFMA (16x16x32), round 16.
// R15 (HW cvt_pk everywhere, sigma fragments, 3rd-MFMA output, pins) +
//  (a) NO LDS: per-wave t is constant -> per-lane row base is loop-invariant;
//      1-deep rolling register prefetch (2 dwordx4/tile, ~1 tile of latency cover).
//      (R5 failed this with per-tile addr recompute + remat; R12 with 4-deep+spill.)
//  (b) exp-form tanh: 1 - 2*rcp(exp2(k*z)+1); 5 inst/elem vs Pade's 9, no clamp,
//      exact saturation at +-inf, err ~1e-6.

typedef __attribute__((ext_vector_type(8))) short bf16x8;
typedef __attribute__((ext_vector_type(4))) float f32x4;

__device__ __forceinline__ unsigned pk2(float lo, float hi) {
    unsigned r;
    asm("v_cvt_pk_bf16_f32 %0, %1, %2" : "=v"(r) : "v"(lo), "v"(hi));
    return r;
}

union BF8 { bf16x8 v; unsigned u[4]; uint4 q; };

// d_ws layout in uint4 (16B) units:
//   [0,256)     WA[lane][T]      bf16x8  (folded W_in', sigma rows, bias col k=24)
//   [256,768)   WI[lane][k0][U]  bf16x8  (W_ih, sigma-permuted rows, natural k)
//   [768,1024)  B2[lane][U]      float4  (b_ih+b_hh, sigma-sliced)
//   [1280,1408) WOA[lane][k0]    bf16x8  (y-MFMA A-frag: row0 = W_out)

__global__ __launch_bounds__(64) void narx_prep(
    const float* __restrict__ W_in, const float* __restrict__ b_in,
    const float* __restrict__ W_ih, const float* __restrict__ b_ih,
    const float* __restrict__ b_hh, const float* __restrict__ W_out,
    uint4* __restrict__ ws)
{
    const int lane = threadIdx.x;        // 64 threads, one wave
    const int c = lane >> 4, pl = lane & 15;

    // layer-1 A-fragments: folded W' (64x32), sigma rows, bias col k=24.
    // sigma: tile T, tile-row pl sources W_in row 8*(pl>>2)+(pl&3)+4*(T&1)+32*(T>>1)
    // so d1 reg (T,q) at lane c holds h_{8c + 4*(T&1) + q + 32*(T>>1)}.
    #pragma unroll
    for (int T = 0; T < 4; ++T) {
        const int r = ((pl >> 2) * 8) + (pl & 3) + (T & 1) * 4 + (T >> 1) * 32;
        const float* W = W_in + r * 32;
        float wr[8];
        if (c == 0) {
            #pragma unroll
            for (int j = 0; j < 7; ++j) wr[j] = W[j] + W[21 + j];
            wr[7] = W[28] + W[31];
        } else if (c == 1) {
            #pragma unroll
            for (int j = 0; j < 7; ++j) wr[j] = W[14 + j];
            wr[7] = W[30];
        } else if (c == 2) {
            #pragma unroll
            for (int j = 0; j < 7; ++j) wr[j] = W[7 + j];
            wr[7] = W[29];
        } else {
            wr[0] = b_in[r];
            #pragma unroll
            for (int j = 1; j < 8; ++j) wr[j] = 0.0f;
        }
        BF8 t;
        t.u[0] = pk2(wr[0], wr[1]); t.u[1] = pk2(wr[2], wr[3]);
        t.u[2] = pk2(wr[4], wr[5]); t.u[3] = pk2(wr[6], wr[7]);
        ws[lane*4 + T] = t.q;
    }

    // layer-2 A-fragments: SAME sigma on W_ih rows, natural k columns.
    // d2 reg (U,q) at lane c holds a_{8c + 4*(U&1) + q + 32*(U>>1)} =
    // exactly the y-MFMA B-fragment after pairing (U=0,1 -> pb0; U=2,3 -> pb1).
    #pragma unroll
    for (int k0 = 0; k0 < 2; ++k0)
    #pragma unroll
    for (int U = 0; U < 4; ++U) {
        const int r = ((pl >> 2) * 8) + (pl & 3) + (U & 1) * 4 + (U >> 1) * 32;
        const float* p = W_ih + r * 64 + 32*k0 + 8*c;
        float4 u0 = *(const float4*)p, u1 = *(const float4*)(p + 4);
        BF8 t;
        t.u[0] = pk2(u0.x, u0.y); t.u[1] = pk2(u0.z, u0.w);
        t.u[2] = pk2(u1.x, u1.y); t.u[3] = pk2(u1.z, u1.w);
        ws[256 + lane*8 + k0*4 + U] = t.q;
    }

    // bias2 sigma-sliced: reg q of tile U at lane c = bias[8c + q + 4*(U&1) + 32*(U>>1)]
    float4* wsf = (float4*)ws;
    #pragma unroll
    for (int U = 0; U < 4; ++U) {
        const int o = 8*c + 4*(U & 1) + 32*(U >> 1);
        wsf[768 + lane*4 + U] = make_float4(b_ih[o+0]+b_hh[o+0], b_ih[o+1]+b_hh[o+1],
                                            b_ih[o+2]+b_hh[o+2], b_ih[o+3]+b_hh[o+3]);
    }

    // y-MFMA A-fragments: A[row=pl][k=32k0+8c+j] = (pl==0 ? W_out[k] : 0)
    #pragma unroll
    for (int k0 = 0; k0 < 2; ++k0) {
        BF8 t;
        if (pl == 0) {
            const float* p = W_out + 32*k0 + 8*c;
            t.u[0] = pk2(p[0], p[1]); t.u[1] = pk2(p[2], p[3]);
            t.u[2] = pk2(p[4], p[5]); t.u[3] = pk2(p[6], p[7]);
        } else {
            t.u[0] = t.u[1] = t.u[2] = t.u[3] = 0u;
        }
        ws[1280 + lane*2 + k0] = t.q;
    }
}

__global__ __launch_bounds__(256, 2) void narx_main(
    const float* __restrict__ x, const uint4* __restrict__ ws,
    const float* __restrict__ b_out, float* __restrict__ out)
{
    // bijective XCD-aware swizzle (m204)
    const int nwg  = gridDim.x;
    const int orig = blockIdx.x;
    const int q8 = nwg >> 3, r8 = nwg & 7;
    const int xcd = orig & 7, inner = orig >> 3;
    const int b = (xcd < r8 ? xcd * (q8 + 1) : r8 * (q8 + 1) + (xcd - r8) * q8) + inner;

    const int lane = threadIdx.x & 63;
    const int c    = lane >> 4;
    const int pl   = lane & 15;
    const int pt0  = 3072 + b * 512 + (int)(threadIdx.x >> 6) * 128;

    // ---- invariant fragment loads (coalesced, L2-hot) ----
    bf16x8 wa[4];
    #pragma unroll
    for (int T = 0; T < 4; ++T) { BF8 t; t.q = ws[lane*4 + T]; wa[T] = t.v; }
    bf16x8 wi[2][4];
    #pragma unroll
    for (int k0 = 0; k0 < 2; ++k0)
    #pragma unroll
    for (int U = 0; U < 4; ++U) { BF8 t; t.q = ws[256 + lane*8 + k0*4 + U]; wi[k0][U] = t.v; }
    bf16x8 woa[2];
    #pragma unroll
    for (int k0 = 0; k0 < 2; ++k0) { BF8 t; t.q = ws[1280 + lane*2 + k0]; woa[k0] = t.v; }
    const float4* wsf = (const float4*)ws;
    f32x4 bias2[4];
    #pragma unroll
    for (int U = 0; U < 4; ++U) {
        float4 v = wsf[768 + lane*4 + U];
        bias2[U] = f32x4{v.x, v.y, v.z, v.w};
    }
    const float bout = b_out[0];
    const f32x4 cy = {c == 0 ? bout : 0.f, 0.f, 0.f, 0.f};
    const f32x4 zero = {0.f, 0.f, 0.f, 0.f};

    // Pin invariants (opaque -> not rematerializable per tile).
    asm volatile("" : "+v"(wa[0]), "+v"(wa[1]), "+v"(wa[2]), "+v"(wa[3]),
                      "+v"(wi[0][0]), "+v"(wi[0][1]), "+v"(wi[0][2]), "+v"(wi[0][3]),
                      "+v"(wi[1][0]), "+v"(wi[1][1]), "+v"(wi[1][2]), "+v"(wi[1][3]),
                      "+v"(bias2[0]), "+v"(bias2[1]), "+v"(bias2[2]), "+v"(bias2[3]),
                      "+v"(woa[0]), "+v"(woa[1]));

    // ---- per-wave-invariant row base: t is CONSTANT across the wave's 128 pts ----
    const int tw  = pt0 >> 10, g0w = pt0 & 1023;
    const int dly = (c < 3) ? c : 0;                 // c==3 loads a dummy row (discarded)
    const float4* pbase = (const float4*)x + ((size_t)(tw - 1 - dly) * 1024 + g0w + pl) * 2;
    const bool c3 = (c == 3);

    // 1-deep rolling prefetch: tile rb+1's row is in flight during tile rb.
    float4 P0 = pbase[0], P1 = pbase[1];

    #pragma unroll
    for (int rb = 0; rb < 8; ++rb) {
        const int m0 = pt0 + rb * 16;
        float4 C0 = P0, C1 = P1;
        if (rb < 7) { P0 = pbase[(rb + 1) * 32]; P1 = pbase[(rb + 1) * 32 + 1]; }

        // B1-fragment: pack this tile's row; c==3 lanes substitute the bias column
        BF8 tv;
        {
            unsigned k0 = pk2(C0.x, C0.y), k1 = pk2(C0.z, C0.w);
            unsigned k2 = pk2(C1.x, C1.y), k3 = pk2(C1.z, C1.w);
            tv.u[0] = c3 ? 0x00003f80u : k0;
            tv.u[1] = c3 ? 0u : k1;
            tv.u[2] = c3 ? 0u : k2;
            tv.u[3] = c3 ? 0u : k3;
        }

        // ---- layer 1: D1 = W'' . X ----
        f32x4 d1[4];
        #pragma unroll
        for (int T = 0; T < 4; ++T)
            d1[T] = __builtin_amdgcn_mfma_f32_16x16x32_bf16(wa[T], tv.v, zero, 0, 0, 0);

        // relu + pack (HW cvt_pk): regs ARE the layer-2 B-fragment (sigma)
        BF8 bh0, bh1;
        bh0.u[0] = pk2(fmaxf(d1[0][0],0.f), fmaxf(d1[0][1],0.f));
        bh0.u[1] = pk2(fmaxf(d1[0][2],0.f), fmaxf(d1[0][3],0.f));
        bh0.u[2] = pk2(fmaxf(d1[1][0],0.f), fmaxf(d1[1][1],0.f));
        bh0.u[3] = pk2(fmaxf(d1[1][2],0.f), fmaxf(d1[1][3],0.f));
        bh1.u[0] = pk2(fmaxf(d1[2][0],0.f), fmaxf(d1[2][1],0.f));
        bh1.u[1] = pk2(fmaxf(d1[2][2],0.f), fmaxf(d1[2][3],0.f));
        bh1.u[2] = pk2(fmaxf(d1[3][0],0.f), fmaxf(d1[3][1],0.f));
        bh1.u[3] = pk2(fmaxf(d1[3][2],0.f), fmaxf(d1[3][3],0.f));

        // ---- layer 2 (sigma-permuted rows) ----
        f32x4 d2[4];
        #pragma unroll
        for (int U = 0; U < 4; ++U) {
            d2[U] = __builtin_amdgcn_mfma_f32_16x16x32_bf16(wi[0][U], bh0.v, bias2[U], 0, 0, 0);
            d2[U] = __builtin_amdgcn_mfma_f32_16x16x32_bf16(wi[1][U], bh1.v, d2[U],   0, 0, 0);
        }

        // ---- tanh = 1 - 2*rcp(exp2(2log2e * z) + 1): 5 inst/elem, exact saturation ----
        f32x4 av[4];
        #pragma unroll
        for (int U = 0; U < 4; ++U) {
            #pragma unroll
            for (int j = 0; j < 4; ++j) {
                float e  = __builtin_amdgcn_exp2f(d2[U][j] * 2.885390081777927f);
                float rc = __builtin_amdgcn_rcpf(e + 1.0f);
                av[U][j] = fmaf(-2.0f, rc, 1.0f);
            }
        }
        BF8 pb0, pb1;
        pb0.u[0] = pk2(av[0][0], av[0][1]); pb0.u[1] = pk2(av[0][2], av[0][3]);
        pb0.u[2] = pk2(av[1][0], av[1][1]); pb0.u[3] = pk2(av[1][2], av[1][3]);
        pb1.u[0] = pk2(av[2][0], av[2][1]); pb1.u[1] = pk2(av[2][2], av[2][3]);
        pb1.u[2] = pk2(av[3][0], av[3][1]); pb1.u[3] = pk2(av[3][2], av[3][3]);

        // ---- layer 3: y row0 = W_out . a + b_out ----
        f32x4 dy;
        dy = __builtin_amdgcn_mfma_f32_16x16x32_bf16(woa[0], pb0.v, cy, 0, 0, 0);
        dy = __builtin_amdgcn_mfma_f32_16x16x32_bf16(woa[1], pb1.v, dy, 0, 0, 0);

        if (lane < 16)
            out[m0 + lane] = dy[0];
    }
}

__global__ __launch_bounds__(256) void narx_pass(const float* __restrict__ x, float* __restrict__ out) {
    const int i = blockIdx.x * 256 + threadIdx.x;   // i < 3072
    out[i] = x[i * 8 + 7];
}

extern "C" void kernel_launch(void* const* d_in, const int* in_sizes, int n_in,
                              void* d_out, int out_size, void* d_ws, size_t ws_size,
                              hipStream_t stream) {
    const float* x     = (const float*)d_in[0];
    const float* W_in  = (const float*)d_in[1];
    const float* b_in  = (const float*)d_in[2];
    const float* W_ih  = (const float*)d_in[3];
    const float* b_ih  = (const float*)d_in[4];
    // d_in[5] = W_hh: unused in the reference forward
    const float* b_hh  = (const float*)d_in[6];
    const float* W_out = (const float*)d_in[7];
    const float* b_out = (const float*)d_in[8];
    float* out = (float*)d_out;
    uint4* ws = (uint4*)d_ws;            // needs ~24 KB

    narx_prep<<<1, 64, 0, stream>>>(W_in, b_in, W_ih, b_ih, b_hh, W_out, ws);
    // points m in [3072, 4096*1024): 4,191,232 = 8186 blocks * 512 pts
    narx_main<<<8186, 256, 0, stream>>>(x, ws, b_out, out);
    narx_pass<<<12, 256, 0, stream>>>(x, out);      // t < 3 passthrough
}

// Round 17
// 104.695 us; speedup vs baseline: 1.1453x; 1.1453x over previous
//
#include <hip/hip_runtime.h>
#include <hip/hip_bf16.h>

// NARX forward via bf16 MFMA (16x16x32), round 17.
// EXACT R15 structure (best verified: 122.6us dispatch / 112.7 total) with ONE
// change: tanh = 1 - 2*rcp(exp2(k*z)+1) instead of Pade(5,4).
// 5 ops/elem (2 trans) vs 9 ops/elem (1 trans); no clamp needed (inf/0 saturate).
// R16's LDS-removal is REVERTED (third confirmation it regresses: R5/R12/R16).

typedef __attribute__((ext_vector_type(8))) short bf16x8;
typedef __attribute__((ext_vector_type(4))) float f32x4;

__device__ __forceinline__ unsigned pk2(float lo, float hi) {
    unsigned r;
    asm("v_cvt_pk_bf16_f32 %0, %1, %2" : "=v"(r) : "v"(lo), "v"(hi));
    return r;
}

union BF8 { bf16x8 v; unsigned u[4]; uint4 q; };

// d_ws layout in uint4 (16B) units:
//   [0,256)     WA[lane][T]      bf16x8  (folded W_in', sigma rows, bias col k=24)
//   [256,768)   WI[lane][k0][U]  bf16x8  (W_ih, sigma-permuted rows, natural k)
//   [768,1024)  B2[lane][U]      float4  (b_ih+b_hh, sigma-sliced)
//   [1280,1408) WOA[lane][k0]    bf16x8  (y-MFMA A-frag: row0 = W_out)

__global__ __launch_bounds__(64) void narx_prep(
    const float* __restrict__ W_in, const float* __restrict__ b_in,
    const float* __restrict__ W_ih, const float* __restrict__ b_ih,
    const float* __restrict__ b_hh, const float* __restrict__ W_out,
    uint4* __restrict__ ws)
{
    const int lane = threadIdx.x;        // 64 threads, one wave
    const int c = lane >> 4, pl = lane & 15;

    // layer-1 A-fragments: folded W' (64x32), sigma rows, bias col k=24.
    // sigma: tile T, tile-row pl sources W_in row 8*(pl>>2)+(pl&3)+4*(T&1)+32*(T>>1)
    // so d1 reg (T,q) at lane c holds h_{8c + 4*(T&1) + q + 32*(T>>1)}.
    #pragma unroll
    for (int T = 0; T < 4; ++T) {
        const int r = ((pl >> 2) * 8) + (pl & 3) + (T & 1) * 4 + (T >> 1) * 32;
        const float* W = W_in + r * 32;
        float wr[8];
        if (c == 0) {
            #pragma unroll
            for (int j = 0; j < 7; ++j) wr[j] = W[j] + W[21 + j];
            wr[7] = W[28] + W[31];
        } else if (c == 1) {
            #pragma unroll
            for (int j = 0; j < 7; ++j) wr[j] = W[14 + j];
            wr[7] = W[30];
        } else if (c == 2) {
            #pragma unroll
            for (int j = 0; j < 7; ++j) wr[j] = W[7 + j];
            wr[7] = W[29];
        } else {
            wr[0] = b_in[r];
            #pragma unroll
            for (int j = 1; j < 8; ++j) wr[j] = 0.0f;
        }
        BF8 t;
        t.u[0] = pk2(wr[0], wr[1]); t.u[1] = pk2(wr[2], wr[3]);
        t.u[2] = pk2(wr[4], wr[5]); t.u[3] = pk2(wr[6], wr[7]);
        ws[lane*4 + T] = t.q;
    }

    // layer-2 A-fragments: SAME sigma on W_ih rows, natural k columns.
    // d2 reg (U,q) at lane c holds a_{8c + 4*(U&1) + q + 32*(U>>1)} =
    // exactly the y-MFMA B-fragment after pairing (U=0,1 -> pb0; U=2,3 -> pb1).
    #pragma unroll
    for (int k0 = 0; k0 < 2; ++k0)
    #pragma unroll
    for (int U = 0; U < 4; ++U) {
        const int r = ((pl >> 2) * 8) + (pl & 3) + (U & 1) * 4 + (U >> 1) * 32;
        const float* p = W_ih + r * 64 + 32*k0 + 8*c;
        float4 u0 = *(const float4*)p, u1 = *(const float4*)(p + 4);
        BF8 t;
        t.u[0] = pk2(u0.x, u0.y); t.u[1] = pk2(u0.z, u0.w);
        t.u[2] = pk2(u1.x, u1.y); t.u[3] = pk2(u1.z, u1.w);
        ws[256 + lane*8 + k0*4 + U] = t.q;
    }

    // bias2 sigma-sliced: reg q of tile U at lane c = bias[8c + q + 4*(U&1) + 32*(U>>1)]
    float4* wsf = (float4*)ws;
    #pragma unroll
    for (int U = 0; U < 4; ++U) {
        const int o = 8*c + 4*(U & 1) + 32*(U >> 1);
        wsf[768 + lane*4 + U] = make_float4(b_ih[o+0]+b_hh[o+0], b_ih[o+1]+b_hh[o+1],
                                            b_ih[o+2]+b_hh[o+2], b_ih[o+3]+b_hh[o+3]);
    }

    // y-MFMA A-fragments: A[row=pl][k=32k0+8c+j] = (pl==0 ? W_out[k] : 0)
    #pragma unroll
    for (int k0 = 0; k0 < 2; ++k0) {
        BF8 t;
        if (pl == 0) {
            const float* p = W_out + 32*k0 + 8*c;
            t.u[0] = pk2(p[0], p[1]); t.u[1] = pk2(p[2], p[3]);
            t.u[2] = pk2(p[4], p[5]); t.u[3] = pk2(p[6], p[7]);
        } else {
            t.u[0] = t.u[1] = t.u[2] = t.u[3] = 0u;
        }
        ws[1280 + lane*2 + k0] = t.q;
    }
}

__global__ __launch_bounds__(256, 2) void narx_main(
    const float* __restrict__ x, const uint4* __restrict__ ws,
    const float* __restrict__ b_out, float* __restrict__ out)
{
    // Per-wave F tile: 128 pts x 32 bf16, 16B-chunk XOR swizzle. Written ONCE.
    __shared__ unsigned short F[4][128][32];

    // bijective XCD-aware swizzle (m204)
    const int nwg  = gridDim.x;
    const int orig = blockIdx.x;
    const int q8 = nwg >> 3, r8 = nwg & 7;
    const int xcd = orig & 7, inner = orig >> 3;
    const int b = (xcd < r8 ? xcd * (q8 + 1) : r8 * (q8 + 1) + (xcd - r8) * q8) + inner;

    const int lane = threadIdx.x & 63;
    const int w    = threadIdx.x >> 6;
    const int c    = lane >> 4;
    const int pl   = lane & 15;
    const int pt0  = 3072 + b * 512 + w * 128;

    // ---- invariant fragment loads (coalesced, L2-hot) ----
    bf16x8 wa[4];
    #pragma unroll
    for (int T = 0; T < 4; ++T) { BF8 t; t.q = ws[lane*4 + T]; wa[T] = t.v; }
    bf16x8 wi[2][4];
    #pragma unroll
    for (int k0 = 0; k0 < 2; ++k0)
    #pragma unroll
    for (int U = 0; U < 4; ++U) { BF8 t; t.q = ws[256 + lane*8 + k0*4 + U]; wi[k0][U] = t.v; }
    bf16x8 woa[2];
    #pragma unroll
    for (int k0 = 0; k0 < 2; ++k0) { BF8 t; t.q = ws[1280 + lane*2 + k0]; woa[k0] = t.v; }
    const float4* wsf = (const float4*)ws;
    f32x4 bias2[4];
    #pragma unroll
    for (int U = 0; U < 4; ++U) {
        float4 v = wsf[768 + lane*4 + U];
        bias2[U] = f32x4{v.x, v.y, v.z, v.w};
    }
    const float bout = b_out[0];
    const f32x4 cy = {c == 0 ? bout : 0.f, 0.f, 0.f, 0.f};
    const f32x4 zero = {0.f, 0.f, 0.f, 0.f};

    // ---- build BOTH F halves up front (12 loads -> pack -> 8 LDS writes) ----
    const float4* xr = (const float4*)x;
    {
        const int p0 = pt0 + lane, p1 = pt0 + 64 + lane;
        const int t0 = p0 >> 10, g0v = p0 & 1023;
        const int t1 = p1 >> 10, g1v = p1 & 1023;
        const size_t a1 = ((size_t)(t0-1)*1024 + g0v)*2, a2 = ((size_t)(t0-2)*1024 + g0v)*2,
                     a3 = ((size_t)(t0-3)*1024 + g0v)*2;
        const size_t d1a = ((size_t)(t1-1)*1024 + g1v)*2, d2a = ((size_t)(t1-2)*1024 + g1v)*2,
                     d3a = ((size_t)(t1-3)*1024 + g1v)*2;
        float4 A0 = xr[a1],  A1 = xr[a1+1],  B0 = xr[a2],  B1 = xr[a2+1],
               C0 = xr[a3],  C1 = xr[a3+1];
        float4 D0 = xr[d1a], D1 = xr[d1a+1], E0 = xr[d2a], E1 = xr[d2a+1],
               G0 = xr[d3a], G1 = xr[d3a+1];
        const int s = (lane >> 1) & 3;
        uint4* Fr0 = (uint4*)&F[w][lane][0];
        Fr0[0 ^ s] = make_uint4(pk2(A0.x,A0.y), pk2(A0.z,A0.w), pk2(A1.x,A1.y), pk2(A1.z,A1.w));
        Fr0[1 ^ s] = make_uint4(pk2(B0.x,B0.y), pk2(B0.z,B0.w), pk2(B1.x,B1.y), pk2(B1.z,B1.w));
        Fr0[2 ^ s] = make_uint4(pk2(C0.x,C0.y), pk2(C0.z,C0.w), pk2(C1.x,C1.y), pk2(C1.z,C1.w));
        Fr0[3 ^ s] = make_uint4(0x00003f80u, 0u, 0u, 0u);
        uint4* Fr1 = (uint4*)&F[w][64 + lane][0];   // (64+lane)>>1 & 3 == s
        Fr1[0 ^ s] = make_uint4(pk2(D0.x,D0.y), pk2(D0.z,D0.w), pk2(D1.x,D1.y), pk2(D1.z,D1.w));
        Fr1[1 ^ s] = make_uint4(pk2(E0.x,E0.y), pk2(E0.z,E0.w), pk2(E1.x,E1.y), pk2(E1.z,E1.w));
        Fr1[2 ^ s] = make_uint4(pk2(G0.x,G0.y), pk2(G0.z,G0.w), pk2(G1.x,G1.y), pk2(G1.z,G1.w));
        Fr1[3 ^ s] = make_uint4(0x00003f80u, 0u, 0u, 0u);
    }
    asm volatile("s_waitcnt lgkmcnt(0)" ::: "memory");   // cross-lane LDS dep within wave
    __builtin_amdgcn_sched_barrier(0);

    // Pin invariants (opaque -> not rematerializable per tile).
    asm volatile("" : "+v"(wa[0]), "+v"(wa[1]), "+v"(wa[2]), "+v"(wa[3]),
                      "+v"(wi[0][0]), "+v"(wi[0][1]), "+v"(wi[0][2]), "+v"(wi[0][3]),
                      "+v"(wi[1][0]), "+v"(wi[1][1]), "+v"(wi[1][2]), "+v"(wi[1][3]),
                      "+v"(bias2[0]), "+v"(bias2[1]), "+v"(bias2[2]), "+v"(bias2[3]),
                      "+v"(woa[0]), "+v"(woa[1]));

    const int s_rd = (pl >> 1) & 3;
    bf16x8 bf1 = *(bf16x8*)&F[w][pl][(c ^ s_rd) * 8];   // hoisted first-tile B1

    #pragma unroll 2
    for (int rb = 0; rb < 8; ++rb) {
        const int m0 = pt0 + rb * 16;

        // ---- layer 1: D1 = W'' . X ----
        f32x4 d1[4];
        #pragma unroll
        for (int T = 0; T < 4; ++T)
            d1[T] = __builtin_amdgcn_mfma_f32_16x16x32_bf16(wa[T], bf1, zero, 0, 0, 0);

        // prefetch next tile's B1 while layer-1 MFMAs are in flight
        {
            const int rn = (rb < 7) ? rb + 1 : 7;
            bf1 = *(bf16x8*)&F[w][rn*16 + pl][(c ^ s_rd) * 8];
        }

        // relu + pack (HW cvt_pk): regs ARE the layer-2 B-fragment (sigma)
        BF8 bh0, bh1;
        bh0.u[0] = pk2(fmaxf(d1[0][0],0.f), fmaxf(d1[0][1],0.f));
        bh0.u[1] = pk2(fmaxf(d1[0][2],0.f), fmaxf(d1[0][3],0.f));
        bh0.u[2] = pk2(fmaxf(d1[1][0],0.f), fmaxf(d1[1][1],0.f));
        bh0.u[3] = pk2(fmaxf(d1[1][2],0.f), fmaxf(d1[1][3],0.f));
        bh1.u[0] = pk2(fmaxf(d1[2][0],0.f), fmaxf(d1[2][1],0.f));
        bh1.u[1] = pk2(fmaxf(d1[2][2],0.f), fmaxf(d1[2][3],0.f));
        bh1.u[2] = pk2(fmaxf(d1[3][0],0.f), fmaxf(d1[3][1],0.f));
        bh1.u[3] = pk2(fmaxf(d1[3][2],0.f), fmaxf(d1[3][3],0.f));

        // ---- layer 2 (sigma-permuted rows) ----
        f32x4 d2[4];
        #pragma unroll
        for (int U = 0; U < 4; ++U) {
            d2[U] = __builtin_amdgcn_mfma_f32_16x16x32_bf16(wi[0][U], bh0.v, bias2[U], 0, 0, 0);
            d2[U] = __builtin_amdgcn_mfma_f32_16x16x32_bf16(wi[1][U], bh1.v, d2[U],   0, 0, 0);
        }

        // ---- tanh = 1 - 2*rcp(exp2(2log2e*z)+1): 5 ops/elem, exact saturation ----
        f32x4 av[4];
        #pragma unroll
        for (int U = 0; U < 4; ++U) {
            #pragma unroll
            for (int j = 0; j < 4; ++j) {
                float e  = __builtin_amdgcn_exp2f(d2[U][j] * 2.885390081777927f);
                float rc = __builtin_amdgcn_rcpf(e + 1.0f);
                av[U][j] = fmaf(-2.0f, rc, 1.0f);
            }
        }
        BF8 pb0, pb1;
        pb0.u[0] = pk2(av[0][0], av[0][1]); pb0.u[1] = pk2(av[0][2], av[0][3]);
        pb0.u[2] = pk2(av[1][0], av[1][1]); pb0.u[3] = pk2(av[1][2], av[1][3]);
        pb1.u[0] = pk2(av[2][0], av[2][1]); pb1.u[1] = pk2(av[2][2], av[2][3]);
        pb1.u[2] = pk2(av[3][0], av[3][1]); pb1.u[3] = pk2(av[3][2], av[3][3]);

        // ---- layer 3: y row0 = W_out . a + b_out ----
        f32x4 dy;
        dy = __builtin_amdgcn_mfma_f32_16x16x32_bf16(woa[0], pb0.v, cy, 0, 0, 0);
        dy = __builtin_amdgcn_mfma_f32_16x16x32_bf16(woa[1], pb1.v, dy, 0, 0, 0);

        if (lane < 16)
            out[m0 + lane] = dy[0];
    }
}

__global__ __launch_bounds__(256) void narx_pass(const float* __restrict__ x, float* __restrict__ out) {
    const int i = blockIdx.x * 256 + threadIdx.x;   // i < 3072
    out[i] = x[i * 8 + 7];
}

extern "C" void kernel_launch(void* const* d_in, const int* in_sizes, int n_in,
                              void* d_out, int out_size, void* d_ws, size_t ws_size,
                              hipStream_t stream) {
    const float* x     = (const float*)d_in[0];
    const float* W_in  = (const float*)d_in[1];
    const float* b_in  = (const float*)d_in[2];
    const float* W_ih  = (const float*)d_in[3];
    const float* b_ih  = (const float*)d_in[4];
    // d_in[5] = W_hh: unused in the reference forward
    const float* b_hh  = (const float*)d_in[6];
    const float* W_out = (const float*)d_in[7];
    const float* b_out = (const float*)d_in[8];
    float* out = (float*)d_out;
    uint4* ws = (uint4*)d_ws;            // needs ~24 KB

    narx_prep<<<1, 64, 0, stream>>>(W_in, b_in, W_ih, b_ih, b_hh, W_out, ws);
    // points m in [3072, 4096*1024): 4,191,232 = 8186 blocks * 512 pts
    narx_main<<<8186, 256, 0, stream>>>(x, ws, b_out, out);
    narx_pass<<<12, 256, 0, stream>>>(x, out);      // t < 3 passthrough
}

// Round 20
// 103.978 us; speedup vs baseline: 1.1532x; 1.0069x over previous
//
#include <hip/hip_runtime.h>
#include <hip/hip_bf16.h>

// NARX forward via bf16 MFMA (16x16x32), round 20 = R17 restored verbatim
// (best verified: 104.7us total / 115.6us dispatch, absmax 0.0078).
// R18/R19's tanh-affine fold is abandoned: two identical unexplained failures
// (absmax 2.759277 with BOTH (256,4) and (256,2)) -> mechanism not understood,
// do not iterate blind. Structure: sigma-permuted fragments (layer1 acc ==
// layer2 B-frag, layer2 acc == layer3 B-frag), 3-MFMA chain per 16-pt tile,
// HW v_cvt_pk_bf16_f32 packing, exp-form tanh, LDS F-tile built once.

typedef __attribute__((ext_vector_type(8))) short bf16x8;
typedef __attribute__((ext_vector_type(4))) float f32x4;

__device__ __forceinline__ unsigned pk2(float lo, float hi) {
    unsigned r;
    asm("v_cvt_pk_bf16_f32 %0, %1, %2" : "=v"(r) : "v"(lo), "v"(hi));
    return r;
}

union BF8 { bf16x8 v; unsigned u[4]; uint4 q; };

// d_ws layout in uint4 (16B) units:
//   [0,256)     WA[lane][T]      bf16x8  (folded W_in', sigma rows, bias col k=24)
//   [256,768)   WI[lane][k0][U]  bf16x8  (W_ih, sigma-permuted rows, natural k)
//   [768,1024)  B2[lane][U]      float4  (b_ih+b_hh, sigma-sliced)
//   [1280,1408) WOA[lane][k0]    bf16x8  (y-MFMA A-frag: row0 = W_out)

__global__ __launch_bounds__(64) void narx_prep(
    const float* __restrict__ W_in, const float* __restrict__ b_in,
    const float* __restrict__ W_ih, const float* __restrict__ b_ih,
    const float* __restrict__ b_hh, const float* __restrict__ W_out,
    uint4* __restrict__ ws)
{
    const int lane = threadIdx.x;        // 64 threads, one wave
    const int c = lane >> 4, pl = lane & 15;

    // layer-1 A-fragments: folded W' (64x32), sigma rows, bias col k=24.
    // sigma: tile T, tile-row pl sources W_in row 8*(pl>>2)+(pl&3)+4*(T&1)+32*(T>>1)
    // so d1 reg (T,q) at lane c holds h_{8c + 4*(T&1) + q + 32*(T>>1)}.
    #pragma unroll
    for (int T = 0; T < 4; ++T) {
        const int r = ((pl >> 2) * 8) + (pl & 3) + (T & 1) * 4 + (T >> 1) * 32;
        const float* W = W_in + r * 32;
        float wr[8];
        if (c == 0) {
            #pragma unroll
            for (int j = 0; j < 7; ++j) wr[j] = W[j] + W[21 + j];
            wr[7] = W[28] + W[31];
        } else if (c == 1) {
            #pragma unroll
            for (int j = 0; j < 7; ++j) wr[j] = W[14 + j];
            wr[7] = W[30];
        } else if (c == 2) {
            #pragma unroll
            for (int j = 0; j < 7; ++j) wr[j] = W[7 + j];
            wr[7] = W[29];
        } else {
            wr[0] = b_in[r];
            #pragma unroll
            for (int j = 1; j < 8; ++j) wr[j] = 0.0f;
        }
        BF8 t;
        t.u[0] = pk2(wr[0], wr[1]); t.u[1] = pk2(wr[2], wr[3]);
        t.u[2] = pk2(wr[4], wr[5]); t.u[3] = pk2(wr[6], wr[7]);
        ws[lane*4 + T] = t.q;
    }

    // layer-2 A-fragments: SAME sigma on W_ih rows, natural k columns.
    // d2 reg (U,q) at lane c holds a_{8c + 4*(U&1) + q + 32*(U>>1)} =
    // exactly the y-MFMA B-fragment after pairing (U=0,1 -> pb0; U=2,3 -> pb1).
    #pragma unroll
    for (int k0 = 0; k0 < 2; ++k0)
    #pragma unroll
    for (int U = 0; U < 4; ++U) {
        const int r = ((pl >> 2) * 8) + (pl & 3) + (U & 1) * 4 + (U >> 1) * 32;
        const float* p = W_ih + r * 64 + 32*k0 + 8*c;
        float4 u0 = *(const float4*)p, u1 = *(const float4*)(p + 4);
        BF8 t;
        t.u[0] = pk2(u0.x, u0.y); t.u[1] = pk2(u0.z, u0.w);
        t.u[2] = pk2(u1.x, u1.y); t.u[3] = pk2(u1.z, u1.w);
        ws[256 + lane*8 + k0*4 + U] = t.q;
    }

    // bias2 sigma-sliced: reg q of tile U at lane c = bias[8c + q + 4*(U&1) + 32*(U>>1)]
    float4* wsf = (float4*)ws;
    #pragma unroll
    for (int U = 0; U < 4; ++U) {
        const int o = 8*c + 4*(U & 1) + 32*(U >> 1);
        wsf[768 + lane*4 + U] = make_float4(b_ih[o+0]+b_hh[o+0], b_ih[o+1]+b_hh[o+1],
                                            b_ih[o+2]+b_hh[o+2], b_ih[o+3]+b_hh[o+3]);
    }

    // y-MFMA A-fragments: A[row=pl][k=32k0+8c+j] = (pl==0 ? W_out[k] : 0)
    #pragma unroll
    for (int k0 = 0; k0 < 2; ++k0) {
        BF8 t;
        if (pl == 0) {
            const float* p = W_out + 32*k0 + 8*c;
            t.u[0] = pk2(p[0], p[1]); t.u[1] = pk2(p[2], p[3]);
            t.u[2] = pk2(p[4], p[5]); t.u[3] = pk2(p[6], p[7]);
        } else {
            t.u[0] = t.u[1] = t.u[2] = t.u[3] = 0u;
        }
        ws[1280 + lane*2 + k0] = t.q;
    }
}

__global__ __launch_bounds__(256, 2) void narx_main(
    const float* __restrict__ x, const uint4* __restrict__ ws,
    const float* __restrict__ b_out, float* __restrict__ out)
{
    // Per-wave F tile: 128 pts x 32 bf16, 16B-chunk XOR swizzle. Written ONCE.
    __shared__ unsigned short F[4][128][32];

    // bijective XCD-aware swizzle (m204)
    const int nwg  = gridDim.x;
    const int orig = blockIdx.x;
    const int q8 = nwg >> 3, r8 = nwg & 7;
    const int xcd = orig & 7, inner = orig >> 3;
    const int b = (xcd < r8 ? xcd * (q8 + 1) : r8 * (q8 + 1) + (xcd - r8) * q8) + inner;

    const int lane = threadIdx.x & 63;
    const int w    = threadIdx.x >> 6;
    const int c    = lane >> 4;
    const int pl   = lane & 15;
    const int pt0  = 3072 + b * 512 + w * 128;

    // ---- invariant fragment loads (coalesced, L2-hot) ----
    bf16x8 wa[4];
    #pragma unroll
    for (int T = 0; T < 4; ++T) { BF8 t; t.q = ws[lane*4 + T]; wa[T] = t.v; }
    bf16x8 wi[2][4];
    #pragma unroll
    for (int k0 = 0; k0 < 2; ++k0)
    #pragma unroll
    for (int U = 0; U < 4; ++U) { BF8 t; t.q = ws[256 + lane*8 + k0*4 + U]; wi[k0][U] = t.v; }
    bf16x8 woa[2];
    #pragma unroll
    for (int k0 = 0; k0 < 2; ++k0) { BF8 t; t.q = ws[1280 + lane*2 + k0]; woa[k0] = t.v; }
    const float4* wsf = (const float4*)ws;
    f32x4 bias2[4];
    #pragma unroll
    for (int U = 0; U < 4; ++U) {
        float4 v = wsf[768 + lane*4 + U];
        bias2[U] = f32x4{v.x, v.y, v.z, v.w};
    }
    const float bout = b_out[0];
    const f32x4 cy = {c == 0 ? bout : 0.f, 0.f, 0.f, 0.f};
    const f32x4 zero = {0.f, 0.f, 0.f, 0.f};

    // ---- build BOTH F halves up front (12 loads -> pack -> 8 LDS writes) ----
    const float4* xr = (const float4*)x;
    {
        const int p0 = pt0 + lane, p1 = pt0 + 64 + lane;
        const int t0 = p0 >> 10, g0v = p0 & 1023;
        const int t1 = p1 >> 10, g1v = p1 & 1023;
        const size_t a1 = ((size_t)(t0-1)*1024 + g0v)*2, a2 = ((size_t)(t0-2)*1024 + g0v)*2,
                     a3 = ((size_t)(t0-3)*1024 + g0v)*2;
        const size_t d1a = ((size_t)(t1-1)*1024 + g1v)*2, d2a = ((size_t)(t1-2)*1024 + g1v)*2,
                     d3a = ((size_t)(t1-3)*1024 + g1v)*2;
        float4 A0 = xr[a1],  A1 = xr[a1+1],  B0 = xr[a2],  B1 = xr[a2+1],
               C0 = xr[a3],  C1 = xr[a3+1];
        float4 D0 = xr[d1a], D1 = xr[d1a+1], E0 = xr[d2a], E1 = xr[d2a+1],
               G0 = xr[d3a], G1 = xr[d3a+1];
        const int s = (lane >> 1) & 3;
        uint4* Fr0 = (uint4*)&F[w][lane][0];
        Fr0[0 ^ s] = make_uint4(pk2(A0.x,A0.y), pk2(A0.z,A0.w), pk2(A1.x,A1.y), pk2(A1.z,A1.w));
        Fr0[1 ^ s] = make_uint4(pk2(B0.x,B0.y), pk2(B0.z,B0.w), pk2(B1.x,B1.y), pk2(B1.z,B1.w));
        Fr0[2 ^ s] = make_uint4(pk2(C0.x,C0.y), pk2(C0.z,C0.w), pk2(C1.x,C1.y), pk2(C1.z,C1.w));
        Fr0[3 ^ s] = make_uint4(0x00003f80u, 0u, 0u, 0u);
        uint4* Fr1 = (uint4*)&F[w][64 + lane][0];   // (64+lane)>>1 & 3 == s
        Fr1[0 ^ s] = make_uint4(pk2(D0.x,D0.y), pk2(D0.z,D0.w), pk2(D1.x,D1.y), pk2(D1.z,D1.w));
        Fr1[1 ^ s] = make_uint4(pk2(E0.x,E0.y), pk2(E0.z,E0.w), pk2(E1.x,E1.y), pk2(E1.z,E1.w));
        Fr1[2 ^ s] = make_uint4(pk2(G0.x,G0.y), pk2(G0.z,G0.w), pk2(G1.x,G1.y), pk2(G1.z,G1.w));
        Fr1[3 ^ s] = make_uint4(0x00003f80u, 0u, 0u, 0u);
    }
    asm volatile("s_waitcnt lgkmcnt(0)" ::: "memory");   // cross-lane LDS dep within wave
    __builtin_amdgcn_sched_barrier(0);

    // Pin invariants (opaque -> not rematerializable per tile).
    asm volatile("" : "+v"(wa[0]), "+v"(wa[1]), "+v"(wa[2]), "+v"(wa[3]),
                      "+v"(wi[0][0]), "+v"(wi[0][1]), "+v"(wi[0][2]), "+v"(wi[0][3]),
                      "+v"(wi[1][0]), "+v"(wi[1][1]), "+v"(wi[1][2]), "+v"(wi[1][3]),
                      "+v"(bias2[0]), "+v"(bias2[1]), "+v"(bias2[2]), "+v"(bias2[3]),
                      "+v"(woa[0]), "+v"(woa[1]));

    const int s_rd = (pl >> 1) & 3;
    bf16x8 bf1 = *(bf16x8*)&F[w][pl][(c ^ s_rd) * 8];   // hoisted first-tile B1

    #pragma unroll 2
    for (int rb = 0; rb < 8; ++rb) {
        const int m0 = pt0 + rb * 16;

        // ---- layer 1: D1 = W'' . X ----
        f32x4 d1[4];
        #pragma unroll
        for (int T = 0; T < 4; ++T)
            d1[T] = __builtin_amdgcn_mfma_f32_16x16x32_bf16(wa[T], bf1, zero, 0, 0, 0);

        // prefetch next tile's B1 while layer-1 MFMAs are in flight
        {
            const int rn = (rb < 7) ? rb + 1 : 7;
            bf1 = *(bf16x8*)&F[w][rn*16 + pl][(c ^ s_rd) * 8];
        }

        // relu + pack (HW cvt_pk): regs ARE the layer-2 B-fragment (sigma)
        BF8 bh0, bh1;
        bh0.u[0] = pk2(fmaxf(d1[0][0],0.f), fmaxf(d1[0][1],0.f));
        bh0.u[1] = pk2(fmaxf(d1[0][2],0.f), fmaxf(d1[0][3],0.f));
        bh0.u[2] = pk2(fmaxf(d1[1][0],0.f), fmaxf(d1[1][1],0.f));
        bh0.u[3] = pk2(fmaxf(d1[1][2],0.f), fmaxf(d1[1][3],0.f));
        bh1.u[0] = pk2(fmaxf(d1[2][0],0.f), fmaxf(d1[2][1],0.f));
        bh1.u[1] = pk2(fmaxf(d1[2][2],0.f), fmaxf(d1[2][3],0.f));
        bh1.u[2] = pk2(fmaxf(d1[3][0],0.f), fmaxf(d1[3][1],0.f));
        bh1.u[3] = pk2(fmaxf(d1[3][2],0.f), fmaxf(d1[3][3],0.f));

        // ---- layer 2 (sigma-permuted rows) ----
        f32x4 d2[4];
        #pragma unroll
        for (int U = 0; U < 4; ++U) {
            d2[U] = __builtin_amdgcn_mfma_f32_16x16x32_bf16(wi[0][U], bh0.v, bias2[U], 0, 0, 0);
            d2[U] = __builtin_amdgcn_mfma_f32_16x16x32_bf16(wi[1][U], bh1.v, d2[U],   0, 0, 0);
        }

        // ---- tanh = 1 - 2*rcp(exp2(2log2e*z)+1): 5 ops/elem, exact saturation ----
        f32x4 av[4];
        #pragma unroll
        for (int U = 0; U < 4; ++U) {
            #pragma unroll
            for (int j = 0; j < 4; ++j) {
                float e  = __builtin_amdgcn_exp2f(d2[U][j] * 2.885390081777927f);
                float rc = __builtin_amdgcn_rcpf(e + 1.0f);
                av[U][j] = fmaf(-2.0f, rc, 1.0f);
            }
        }
        BF8 pb0, pb1;
        pb0.u[0] = pk2(av[0][0], av[0][1]); pb0.u[1] = pk2(av[0][2], av[0][3]);
        pb0.u[2] = pk2(av[1][0], av[1][1]); pb0.u[3] = pk2(av[1][2], av[1][3]);
        pb1.u[0] = pk2(av[2][0], av[2][1]); pb1.u[1] = pk2(av[2][2], av[2][3]);
        pb1.u[2] = pk2(av[3][0], av[3][1]); pb1.u[3] = pk2(av[3][2], av[3][3]);

        // ---- layer 3: y row0 = W_out . a + b_out ----
        f32x4 dy;
        dy = __builtin_amdgcn_mfma_f32_16x16x32_bf16(woa[0], pb0.v, cy, 0, 0, 0);
        dy = __builtin_amdgcn_mfma_f32_16x16x32_bf16(woa[1], pb1.v, dy, 0, 0, 0);

        if (lane < 16)
            out[m0 + lane] = dy[0];
    }
}

__global__ __launch_bounds__(256) void narx_pass(const float* __restrict__ x, float* __restrict__ out) {
    const int i = blockIdx.x * 256 + threadIdx.x;   // i < 3072
    out[i] = x[i * 8 + 7];
}

extern "C" void kernel_launch(void* const* d_in, const int* in_sizes, int n_in,
                              void* d_out, int out_size, void* d_ws, size_t ws_size,
                              hipStream_t stream) {
    const float* x     = (const float*)d_in[0];
    const float* W_in  = (const float*)d_in[1];
    const float* b_in  = (const float*)d_in[2];
    const float* W_ih  = (const float*)d_in[3];
    const float* b_ih  = (const float*)d_in[4];
    // d_in[5] = W_hh: unused in the reference forward
    const float* b_hh  = (const float*)d_in[6];
    const float* W_out = (const float*)d_in[7];
    const float* b_out = (const float*)d_in[8];
    float* out = (float*)d_out;
    uint4* ws = (uint4*)d_ws;            // needs ~24 KB

    narx_prep<<<1, 64, 0, stream>>>(W_in, b_in, W_ih, b_ih, b_hh, W_out, ws);
    // points m in [3072, 4096*1024): 4,191,232 = 8186 blocks * 512 pts
    narx_main<<<8186, 256, 0, stream>>>(x, ws, b_out, out);
    narx_pass<<<12, 256, 0, stream>>>(x, out);      // t < 3 passthrough
}